// Round 3
// baseline (209.701 us; speedup 1.0000x reference)
//
#include <hip/hip_runtime.h>
#include <math.h>

#define NB 32
#define CC 64
#define LL 1024
#define EPS 1e-6f
#define SCALE 14.42695040888963f   // 10*log2(e): exp(10*s) == exp2(SCALE*s)

typedef __attribute__((ext_vector_type(8))) __bf16 bf16x8;
typedef __attribute__((ext_vector_type(4))) float f32x4;

#define GLB(p) ((__attribute__((address_space(1))) void*)(p))
#define LDS(p) ((__attribute__((address_space(3))) void*)(p))

// ws byte layout:
//   At      @ 0         (4 MB)   bf16 [32][1024][64]  rgb, normalized*SCALE, [l][c]
//   Bt      @ 4194304   (4 MB)   bf16 [32][1024][64]  ir, normalized, [l][c]
//   row_sum @ 8388608   (128 KB) f32[32768]   (final, written by merge)
//   col_sum @ 8519680   (128 KB) f32[32768]
//   row_pk  @ 8650752   (128 KB) u32[32768]  (expbits&~1023)|(1023-j)
//   col_pk  @ 8781824   (128 KB) u32[32768]  (expbits&~1023)|(1023-i)
//   partial @ 8912896   (256 B)  f32[64] loss partials
//   rps     @ 9437184   (256 KB) f32[2][32768]      row-sum partials per j-half
//   rpp     @ 9699328   (256 KB) u32[2][32768]      row-pk  partials per j-half
//   cps     @ 9961472   (2 MB)   f32[32][16][1024]  col-sum partials per i-tile
//   cpp     @ 12058624  (2 MB)   u32[32][16][1024]  col-pk  partials per i-tile
// No zero-init needed: every scratch word is direct-stored exactly once.

__global__ __launch_bounds__(256) void transpose_norm_kernel(
        const float* __restrict__ rgb, const float* __restrict__ ir,
        __bf16* __restrict__ At, __bf16* __restrict__ Bt) {
    __shared__ float tile[64][65];
    __shared__ float red[4][64];
    __shared__ float rn[64];

    const int t   = threadIdx.x;
    const int blk = blockIdx.x;
    const int in  = blk >> 9;
    const int b   = (blk >> 4) & 31;
    const int l0  = (blk & 15) << 6;
    const float* src = in ? ir : rgb;
    __bf16*      dst = in ? Bt : At;
    const float  sc  = in ? 1.0f : SCALE;   // fold exp2 prescale into rgb side

    const int ll = t & 63, cg = t >> 6;
    const float* sp = src + ((size_t)b << 16) + l0 + ll;
#pragma unroll
    for (int u = 0; u < 16; ++u) {
        int c = cg * 16 + u;
        tile[c][ll] = sp[(size_t)c << 10];
    }
    __syncthreads();

    float ssq = 0.f;
#pragma unroll
    for (int u = 0; u < 16; ++u) {
        float v = tile[cg * 16 + u][ll];
        ssq = fmaf(v, v, ssq);
    }
    red[cg][ll] = ssq;
    __syncthreads();
    if (t < 64) {
        float s = red[0][t] + red[1][t] + red[2][t] + red[3][t];
        rn[t] = sc / fmaxf(sqrtf(s), 1e-12f);
    }
    __syncthreads();

    const int lw  = t >> 2;
    const int cg2 = t & 3;
    const float r = rn[lw];
    bf16x8 v0, v1;
#pragma unroll
    for (int u = 0; u < 8; ++u)
        v0[u] = (__bf16)(tile[cg2 * 16 + u][lw] * r);
#pragma unroll
    for (int u = 0; u < 8; ++u)
        v1[u] = (__bf16)(tile[cg2 * 16 + 8 + u][lw] * r);
    size_t base = ((((size_t)b << 10) + l0 + lw) << 6) + cg2 * 16;
    *(bf16x8*)(dst + base)     = v0;
    *(bf16x8*)(dst + base + 8) = v1;
}

// Single-pass GEMM: S computed ONCE. Grid 1024 = batch(32) x itile(16) x
// jhalf(2): block owns rows [i0,+64) x cols [jh*512,+512).
//
// r7 lesson: in-loop DS atomics collapsed VALUBusy to 14% (same-address
// serialization + in-order DS gating fragment reads). r8 lesson: register
// col partials + per-chunk shfl tails recovered 29 us but the gemm is STILL
// stall-bound (~25 us vs ~4 us VALU floor): the 32 ds_swizzle + masked
// stores per chunk tail sit on the critical path between compute and
// barrier, and VGPR=52 means no cross-u pipelining.
//
// r9 fix: fully static-unroll the 4-chunk loop; col partials live in
// REGISTERS cs[4][8]/cp[4][8] (all indices compile-time -> no scratch).
// Steady state per chunk = {issue 16 global_load_lds} || {8x(2 ds_read_b128,
// 2 MFMA, exp/pack VALU)} + one barrier. Zero DS-swizzle, zero stores
// in-loop. Single epilogue: q-fold shfl (once), cross-wave fold through the
// retired Bs LDS, ONE col partial per (block,j) -> 4 MB scratch (was 16).
//
// Staging: async global->LDS via global_load_lds, double-buffered; swizzle
// on the GLOBAL side (segment s of row r lands at slot s^(r&7)).
__global__ __launch_bounds__(256, 4) void gemm_stats_kernel(
        const __bf16* __restrict__ At, const __bf16* __restrict__ Bt,
        float* __restrict__ rps, unsigned* __restrict__ rpp,
        float* __restrict__ cps, unsigned* __restrict__ cpp) {
    __shared__ union {
        __bf16 bs[2][8192];                       // 2 x 16 KB (128 rows x 64)
        struct { float fsum[4][512]; unsigned fpk[4][512]; } fold;  // 16 KB
    } sm;

    const int t   = threadIdx.x;
    const int blk = blockIdx.x;
    const int jh  = blk & 1;
    const int it  = (blk >> 1) & 15;
    const int bb  = blk >> 5;
    const int i0  = it << 6;
    const int w = t >> 6, lane = t & 63;
    const int m = lane & 15, q = lane >> 4;

    const size_t bbase = (size_t)bb << 16;
    const __bf16* Bg = Bt + bbase + ((size_t)jh << 15);   // + jh*512 rows*64

    // A fragments (held all kernel): row = i0+16w+m, k = q*8 (+32).
    const __bf16* Ap = At + bbase + ((size_t)(i0 + 16 * w + m) << 6) + q * 8;
    const bf16x8 a0 = *(const bf16x8*)(Ap);
    const bf16x8 a1 = *(const bf16x8*)(Ap + 32);

    // Swizzled fragment read offsets (elements).
    const int mbase = m * 64;
    const int s0 = (q ^ (m & 7)) << 3;
    const int s1 = ((q ^ 4) ^ (m & 7)) << 3;

    float    rsum[4] = {0.f, 0.f, 0.f, 0.f};
    unsigned rpk4[4] = {0u, 0u, 0u, 0u};
    float    cs[4][8];     // col-sum partial, [chunk][u] — static indexed
    unsigned cp[4][8];     // col-pk  partial

    // iinv for this thread's 4 rows: K1023 - r, r=0..3 (low 10 bits of pack).
    const unsigned K1023 = 1023u - (unsigned)(i0 + 16 * w + 4 * q);

    // Per-thread staging geometry: row r = rho*32 + (t>>3), seg slot t&7,
    // global seg = slot ^ (r&7).
    const int sr  = t >> 3;
    const int ssl = t & 7;

    // stage chunk 0 -> bs[0]
#pragma unroll
    for (int rho = 0; rho < 4; ++rho) {
        int r  = rho * 32 + sr;
        int sg = ssl ^ (r & 7);
        const __bf16* gp = Bg + ((size_t)r << 6) + sg * 8;
        __builtin_amdgcn_global_load_lds(GLB(gp),
                LDS(&sm.bs[0][(rho << 11) + (w << 9)]), 16, 0, 0);
    }
    __syncthreads();   // chunk 0 ready

#pragma unroll
    for (int c = 0; c < 4; ++c) {
        const int cur = c & 1;
        if (c < 3) {   // issue async loads for chunk c+1 into the other buffer
#pragma unroll
            for (int rho = 0; rho < 4; ++rho) {
                int r  = rho * 32 + sr;
                int sg = ssl ^ (r & 7);
                const __bf16* gp = Bg + ((size_t)((c + 1) * 128 + r) << 6) + sg * 8;
                __builtin_amdgcn_global_load_lds(GLB(gp),
                        LDS(&sm.bs[cur ^ 1][(rho << 11) + (w << 9)]), 16, 0, 0);
            }
        }
        const __bf16* pb0 = &sm.bs[cur][mbase + s0];
        const __bf16* pb1 = &sm.bs[cur][mbase + s1];
#pragma unroll
        for (int u = 0; u < 8; ++u) {
            bf16x8 b0 = *(const bf16x8*)(pb0 + (u << 10));
            bf16x8 b1 = *(const bf16x8*)(pb1 + (u << 10));
            f32x4 acc = (f32x4){0.f, 0.f, 0.f, 0.f};
            acc = __builtin_amdgcn_mfma_f32_16x16x32_bf16(a0, b0, acc, 0, 0, 0);
            acc = __builtin_amdgcn_mfma_f32_16x16x32_bf16(a1, b1, acc, 0, 0, 0);
            // C/D layout (verified r2-r6): row = i0+16w+4q+r, col = 16ct+m
            // (ct global: jh folded in).
            const int ct = (jh << 5) + (c << 3) + u;
            const unsigned jinv = 1023u - (unsigned)((ct << 4) + m);
            float csv = 0.f;
            unsigned pcv = 0u;
#pragma unroll
            for (int r = 0; r < 4; ++r) {
                float e = __builtin_amdgcn_exp2f(acc[r]);   // SCALE folded in At
                unsigned eb = __float_as_uint(e) & 0xFFFFFC00u;
                rsum[r] += e;
                unsigned pr = eb | jinv;
                rpk4[r] = rpk4[r] > pr ? rpk4[r] : pr;      // v_max_u32
                unsigned pcr = eb + (K1023 - (unsigned)r);  // == eb | iinv
                if (r == 0) { csv = e; pcv = pcr; }
                else        { csv += e; pcv = pcv > pcr ? pcv : pcr; }
            }
            cs[c][u] = csv;   // compile-time indices — stays in registers
            cp[c][u] = pcv;
        }
        // Orders: (a) chunk c+1's loads complete, (b) all waves done reading
        // buf cur before chunk c+1 re-stages it. Also (c==3) retires bs for
        // the epilogue fold reuse.
        __syncthreads();
    }

    // Row stats: one butterfly over the 16 m-lanes (this j-half complete).
#pragma unroll
    for (int s = 1; s < 16; s <<= 1) {
#pragma unroll
        for (int r = 0; r < 4; ++r) {
            rsum[r] += __shfl_xor(rsum[r], s, 64);
            unsigned o = (unsigned)__shfl_xor((int)rpk4[r], s, 64);
            if (o > rpk4[r]) rpk4[r] = o;
        }
    }
    if (m == 0) {
#pragma unroll
        for (int r = 0; r < 4; ++r) {
            int idx = (bb << 10) + i0 + 16 * w + 4 * q + r;
            rps[(jh << 15) + idx] = rsum[r];
            rpp[(jh << 15) + idx] = rpk4[r];
        }
    }

    // Col stats epilogue (once per kernel): fold the 4 q-lanes via shfl,
    // park per-wave results in the retired Bs LDS, cross-wave fold, store
    // ONE partial per (block, col).
#pragma unroll
    for (int c = 0; c < 4; ++c) {
#pragma unroll
        for (int u = 0; u < 8; ++u) {
            float s = cs[c][u];
            s += __shfl_xor(s, 16, 64);
            s += __shfl_xor(s, 32, 64);
            unsigned p = cp[c][u];
            unsigned o = (unsigned)__shfl_xor((int)p, 16, 64);
            if (o > p) p = o;
            o = (unsigned)__shfl_xor((int)p, 32, 64);
            if (o > p) p = o;
            if (q == 0) {
                int jl = (c << 7) + (u << 4) + m;   // 0..511 within j-half
                sm.fold.fsum[w][jl] = s;
                sm.fold.fpk[w][jl]  = p;
            }
        }
    }
    __syncthreads();
#pragma unroll
    for (int v = 0; v < 2; ++v) {
        int jl = (v << 8) + t;
        float s = sm.fold.fsum[0][jl] + sm.fold.fsum[1][jl]
                + sm.fold.fsum[2][jl] + sm.fold.fsum[3][jl];
        unsigned p = sm.fold.fpk[0][jl];
        unsigned o;
        o = sm.fold.fpk[1][jl]; if (o > p) p = o;
        o = sm.fold.fpk[2][jl]; if (o > p) p = o;
        o = sm.fold.fpk[3][jl]; if (o > p) p = o;
        int gidx = (((bb << 4) + it) << 10) + (jh << 9) + jl;
        cps[gidx] = s;
        cpp[gidx] = p;
    }
}

// Fold row partials (2 j-halves) and col partials (16 i-tiles) into the
// final stats arrays. Tie-break: umax on packed (bits|inv_index) keeps the
// smaller index on equal truncated value = first-occurrence, matching ref.
__global__ __launch_bounds__(256) void merge_kernel(
        const float* __restrict__ rps, const unsigned* __restrict__ rpp,
        const float* __restrict__ cps, const unsigned* __restrict__ cpp,
        float* __restrict__ row_sum, unsigned* __restrict__ row_pk,
        float* __restrict__ col_sum, unsigned* __restrict__ col_pk) {
    int p = blockIdx.x * 256 + threadIdx.x;   // 32768
    // rows: 2 partials
    float rs = rps[p] + rps[32768 + p];
    unsigned ra = rpp[p], rb = rpp[32768 + p];
    row_sum[p] = rs;
    row_pk[p]  = ra > rb ? ra : rb;
    // cols: 16 partials, stride 1024 dwords (j contiguous -> coalesced)
    int bb = p >> 10, j = p & 1023;
    const float*    cq = cps + (((size_t)bb << 14) + j);
    const unsigned* cr = cpp + (((size_t)bb << 14) + j);
    float s = 0.f;
    unsigned pk = 0u;
#pragma unroll
    for (int k = 0; k < 16; ++k) {
        s += cq[(size_t)k << 10];
        unsigned o = cr[(size_t)k << 10];
        pk = pk > o ? pk : o;
    }
    col_sum[p] = s;
    col_pk[p]  = pk;
}

// Reference broadcasting: trailing /(sum+EPS) factors are indexed by ELEMENT
// position, not by argmax. Writes per-block partials (no atomics, no init).
__global__ __launch_bounds__(256) void loss_kernel2(
        const float* __restrict__ row_sum, const unsigned* __restrict__ row_pk,
        const float* __restrict__ col_sum, const unsigned* __restrict__ col_pk,
        float* __restrict__ partial) {
    int t = blockIdx.x * 256 + threadIdx.x;
    float acc = 0.f;
#pragma unroll
    for (int it = 0; it < 4; ++it) {
        int p = t + it * 16384;
        if (p < NB * LL) {
            unsigned pk2 = row_pk[p];
            float m2 = __uint_as_float(pk2 & 0xFFFFFC00u);
            int j = 1023 - (int)(pk2 & 1023u);
            float s2 = row_sum[p];
            float s1 = col_sum[p];
            unsigned pk1 = col_pk[(p & ~1023) + j];
            float m1 = __uint_as_float(pk1 & 0xFFFFFC00u);
            acc += logf((m2 / (s2 + EPS)) * (m1 / (s1 + EPS)));
        } else {
            int p2 = p - NB * LL;
            unsigned pk1 = col_pk[p2];
            float m1 = __uint_as_float(pk1 & 0xFFFFFC00u);
            int i = 1023 - (int)(pk1 & 1023u);
            float s1 = col_sum[p2];
            float s2 = row_sum[p2];
            unsigned pk2 = row_pk[(p2 & ~1023) + i];
            float m2 = __uint_as_float(pk2 & 0xFFFFFC00u);
            acc += logf((m1 / (s1 + EPS)) * (m2 / (s2 + EPS)));
        }
    }
#pragma unroll
    for (int off = 32; off > 0; off >>= 1) acc += __shfl_down(acc, off, 64);
    __shared__ float wsum[4];
    int lane = threadIdx.x & 63, w = threadIdx.x >> 6;
    if (lane == 0) wsum[w] = acc;
    __syncthreads();
    if (threadIdx.x == 0)
        partial[blockIdx.x] = wsum[0] + wsum[1] + wsum[2] + wsum[3];
}

__global__ void finalize_kernel(const float* __restrict__ partial,
                                float* __restrict__ out) {
    float v = partial[threadIdx.x];
#pragma unroll
    for (int off = 32; off > 0; off >>= 1) v += __shfl_down(v, off, 64);
    if (threadIdx.x == 0) out[0] = -v / (float)(2 * NB * LL);
}

extern "C" void kernel_launch(void* const* d_in, const int* in_sizes, int n_in,
                              void* d_out, int out_size, void* d_ws, size_t ws_size,
                              hipStream_t stream) {
    const float* rgb = (const float*)d_in[0];
    const float* ir  = (const float*)d_in[1];
    char* wsb = (char*)d_ws;

    __bf16*   At      = (__bf16*)(wsb);
    __bf16*   Bt      = (__bf16*)(wsb + 4194304);
    float*    row_sum = (float*)(wsb + 8388608);
    float*    col_sum = (float*)(wsb + 8519680);
    unsigned* row_pk  = (unsigned*)(wsb + 8650752);
    unsigned* col_pk  = (unsigned*)(wsb + 8781824);
    float*    partial = (float*)(wsb + 8912896);
    float*    rps     = (float*)(wsb + 9437184);
    unsigned* rpp     = (unsigned*)(wsb + 9699328);
    float*    cps     = (float*)(wsb + 9961472);
    unsigned* cpp     = (unsigned*)(wsb + 12058624);

    transpose_norm_kernel<<<1024, 256, 0, stream>>>(rgb, ir, At, Bt);
    gemm_stats_kernel<<<1024, 256, 0, stream>>>(At, Bt, rps, rpp, cps, cpp);
    merge_kernel<<<128, 256, 0, stream>>>(rps, rpp, cps, cpp,
                                          row_sum, row_pk, col_sum, col_pk);
    loss_kernel2<<<64, 256, 0, stream>>>(row_sum, row_pk, col_sum, col_pk, partial);
    finalize_kernel<<<1, 64, 0, stream>>>(partial, (float*)d_out);
}

// Round 4
// 91.489 us; speedup vs baseline: 2.2921x; 2.2921x over previous
//
#include <hip/hip_runtime.h>
#include <math.h>

#define NB 32
#define CC 64
#define LL 1024
#define EPS 1e-6f
#define SCALE 14.42695040888963f   // 10*log2(e): exp(10*s) == exp2(SCALE*s)

typedef __attribute__((ext_vector_type(8))) __bf16 bf16x8;
typedef __attribute__((ext_vector_type(4))) float f32x4;

#define GLB(p) ((__attribute__((address_space(1))) void*)(p))
#define LDS(p) ((__attribute__((address_space(3))) void*)(p))

// ws byte layout:
//   At      @ 0         (4 MB)   bf16 [32][1024][64]  rgb, normalized*SCALE, [l][c]
//   Bt      @ 4194304   (4 MB)   bf16 [32][1024][64]  ir, normalized, [l][c]
//   row_sum @ 8388608   (128 KB) f32[32768]   (final, written by merge)
//   col_sum @ 8519680   (128 KB) f32[32768]
//   row_pk  @ 8650752   (128 KB) u32[32768]  (expbits&~1023)|(1023-j)
//   col_pk  @ 8781824   (128 KB) u32[32768]  (expbits&~1023)|(1023-i)
//   partial @ 8912896   (256 B)  f32[64] loss partials
//   rps     @ 9437184   (256 KB) f32[2][32768]      row-sum partials per j-half
//   rpp     @ 9699328   (256 KB) u32[2][32768]      row-pk  partials per j-half
//   cps     @ 9961472   (2 MB)   f32[32][16][1024]  col-sum partials per i-tile
//   cpp     @ 12058624  (2 MB)   u32[32][16][1024]  col-pk  partials per i-tile
// No zero-init needed: every scratch word is direct-stored exactly once.

__global__ __launch_bounds__(256) void transpose_norm_kernel(
        const float* __restrict__ rgb, const float* __restrict__ ir,
        __bf16* __restrict__ At, __bf16* __restrict__ Bt) {
    __shared__ float tile[64][65];
    __shared__ float red[4][64];
    __shared__ float rn[64];

    const int t   = threadIdx.x;
    const int blk = blockIdx.x;
    const int in  = blk >> 9;
    const int b   = (blk >> 4) & 31;
    const int l0  = (blk & 15) << 6;
    const float* src = in ? ir : rgb;
    __bf16*      dst = in ? Bt : At;
    const float  sc  = in ? 1.0f : SCALE;   // fold exp2 prescale into rgb side

    const int ll = t & 63, cg = t >> 6;
    const float* sp = src + ((size_t)b << 16) + l0 + ll;
#pragma unroll
    for (int u = 0; u < 16; ++u) {
        int c = cg * 16 + u;
        tile[c][ll] = sp[(size_t)c << 10];
    }
    __syncthreads();

    float ssq = 0.f;
#pragma unroll
    for (int u = 0; u < 16; ++u) {
        float v = tile[cg * 16 + u][ll];
        ssq = fmaf(v, v, ssq);
    }
    red[cg][ll] = ssq;
    __syncthreads();
    if (t < 64) {
        float s = red[0][t] + red[1][t] + red[2][t] + red[3][t];
        rn[t] = sc / fmaxf(sqrtf(s), 1e-12f);
    }
    __syncthreads();

    const int lw  = t >> 2;
    const int cg2 = t & 3;
    const float r = rn[lw];
    bf16x8 v0, v1;
#pragma unroll
    for (int u = 0; u < 8; ++u)
        v0[u] = (__bf16)(tile[cg2 * 16 + u][lw] * r);
#pragma unroll
    for (int u = 0; u < 8; ++u)
        v1[u] = (__bf16)(tile[cg2 * 16 + 8 + u][lw] * r);
    size_t base = ((((size_t)b << 10) + l0 + lw) << 6) + cg2 * 16;
    *(bf16x8*)(dst + base)     = v0;
    *(bf16x8*)(dst + base + 8) = v1;
}

// Single-pass GEMM: S computed ONCE. Grid 1024 = batch(32) x itile(16) x
// jhalf(2): block owns rows [i0,+64) x cols [jh*512,+512).
//
// History: r7 in-loop DS atomics -> 14% VALUBusy (serialization). r8
// per-chunk shfl tails -> per-phase cost doubled vs the lean r0 loop.
// r9 held 64 partial dwords live all-kernel -> scratch spill (FETCH 152 MB,
// WRITE 264 MB, 140 us). Conclusion: partials may live at most ONE chunk,
// and nothing serial may sit between compute and barrier.
//
// r10 structure: the block's whole B-half panel is 64 KB -> stage it ONCE
// (full-resident, 4 regions x 16 KB), one vmcnt-draining barrier, then 4
// compute phases separated by CHEAP barriers (no global ops in flight ->
// lgkm-only drain). After phase c, LDS region c is dead: the tail writes
// each lane's r-folded (colsum, colpk) pair into it as 8 fire-and-forget
// ds_write_b64 (covered by the next barrier's lgkmcnt). Once-per-kernel
// epilogue folds the 16 row-groups per column through LDS and stores ONE
// partial per (block,col) -> 4 MB scratch. cs8/cp8 live one chunk only
// (16 dwords, r8-proven no-spill). LDS 64 KB -> 2 blocks/CU,
// __launch_bounds__(256,2) -> VGPR cap 256, spill impossible.
__global__ __launch_bounds__(256, 2) void gemm_stats_kernel(
        const __bf16* __restrict__ At, const __bf16* __restrict__ Bt,
        float* __restrict__ rps, unsigned* __restrict__ rpp,
        float* __restrict__ cps, unsigned* __restrict__ cpp) {
    __shared__ __bf16 bs[32768];   // 64 KB: 4 regions x (128 rows x 64 bf16)

    const int t   = threadIdx.x;
    const int blk = blockIdx.x;
    const int jh  = blk & 1;
    const int it  = (blk >> 1) & 15;
    const int bb  = blk >> 5;
    const int i0  = it << 6;
    const int w = t >> 6, lane = t & 63;
    const int m = lane & 15, q = lane >> 4;

    const size_t bbase = (size_t)bb << 16;
    const __bf16* Bg = Bt + bbase + ((size_t)jh << 15);   // + jh*512 rows*64

    // A fragments (held all kernel): row = i0+16w+m, k = q*8 (+32).
    const __bf16* Ap = At + bbase + ((size_t)(i0 + 16 * w + m) << 6) + q * 8;
    const bf16x8 a0 = *(const bf16x8*)(Ap);
    const bf16x8 a1 = *(const bf16x8*)(Ap + 32);

    // Swizzled fragment read offsets (elements); global-side swizzle puts
    // segment s of row r at slot s^(r&7).
    const int mbase = m * 64;
    const int s0 = (q ^ (m & 7)) << 3;
    const int s1 = ((q ^ 4) ^ (m & 7)) << 3;

    float    rsum[4] = {0.f, 0.f, 0.f, 0.f};
    unsigned rpk4[4] = {0u, 0u, 0u, 0u};

    // iinv for this thread's 4 rows: K1023 - r, r=0..3 (low 10 bits of pack).
    const unsigned K1023 = 1023u - (unsigned)(i0 + 16 * w + 4 * q);

    // Staging geometry (verbatim per region): row r = rho*32 + (t>>3),
    // seg slot t&7, global seg = slot ^ (r&7).
    const int sr  = t >> 3;
    const int ssl = t & 7;

    // Stage the WHOLE panel: 4 regions x 128 rows.
#pragma unroll
    for (int c = 0; c < 4; ++c) {
#pragma unroll
        for (int rho = 0; rho < 4; ++rho) {
            int r  = rho * 32 + sr;
            int sg = ssl ^ (r & 7);
            const __bf16* gp = Bg + ((size_t)(c * 128 + r) << 6) + sg * 8;
            __builtin_amdgcn_global_load_lds(GLB(gp),
                    LDS(&bs[c * 8192 + (rho << 11) + (w << 9)]), 16, 0, 0);
        }
    }
    __syncthreads();   // the ONLY vmcnt-draining barrier

    float2* tl = (float2*)bs;   // tail alias: region c = tl[c*2048 .. +2048)

    for (int c = 0; c < 4; ++c) {
        float    cs8[8];
        unsigned cp8[8];
        const __bf16* pb0 = &bs[c * 8192 + mbase + s0];
        const __bf16* pb1 = &bs[c * 8192 + mbase + s1];
#pragma unroll
        for (int u = 0; u < 8; ++u) {
            bf16x8 b0 = *(const bf16x8*)(pb0 + (u << 10));
            bf16x8 b1 = *(const bf16x8*)(pb1 + (u << 10));
            f32x4 acc = (f32x4){0.f, 0.f, 0.f, 0.f};
            acc = __builtin_amdgcn_mfma_f32_16x16x32_bf16(a0, b0, acc, 0, 0, 0);
            acc = __builtin_amdgcn_mfma_f32_16x16x32_bf16(a1, b1, acc, 0, 0, 0);
            // C/D layout (verified r2-r6): row = i0+16w+4q+r, col = 16ct+m.
            const int ct = (jh << 5) + (c << 3) + u;
            const unsigned jinv = 1023u - (unsigned)((ct << 4) + m);
            float csv = 0.f;
            unsigned pcv = 0u;
#pragma unroll
            for (int r = 0; r < 4; ++r) {
                float e = __builtin_amdgcn_exp2f(acc[r]);   // SCALE folded in At
                unsigned eb = __float_as_uint(e) & 0xFFFFFC00u;
                rsum[r] += e;
                unsigned pr = eb | jinv;
                rpk4[r] = rpk4[r] > pr ? rpk4[r] : pr;      // v_max_u32
                unsigned pcr = eb + (K1023 - (unsigned)r);  // == eb | iinv
                if (r == 0) { csv = e; pcv = pcr; }
                else        { csv += e; pcv = pcv > pcr ? pcv : pcr; }
            }
            cs8[u] = csv;   // live within this chunk only (r8-proven no-spill)
            cp8[u] = pcv;
        }
        // All waves done READING region c -> it becomes the tail buffer.
        // Cheap barrier: no global ops in flight, lgkm-only drain.
        __syncthreads();
#pragma unroll
        for (int u = 0; u < 8; ++u) {
            float2 v;
            v.x = cs8[u];
            v.y = __uint_as_float(cp8[u]);
            tl[c * 2048 + (w * 8 + u) * 64 + lane] = v;   // ds_write_b64
        }
    }
    __syncthreads();   // tails visible (barrier drains lgkmcnt)

    // Row stats: one butterfly over the 16 m-lanes (this j-half complete).
#pragma unroll
    for (int s = 1; s < 16; s <<= 1) {
#pragma unroll
        for (int r = 0; r < 4; ++r) {
            rsum[r] += __shfl_xor(rsum[r], s, 64);
            unsigned o = (unsigned)__shfl_xor((int)rpk4[r], s, 64);
            if (o > rpk4[r]) rpk4[r] = o;
        }
    }
    if (m == 0) {
#pragma unroll
        for (int r = 0; r < 4; ++r) {
            int idx = (bb << 10) + i0 + 16 * w + 4 * q + r;
            rps[(jh << 15) + idx] = rsum[r];
            rpp[(jh << 15) + idx] = rpk4[r];
        }
    }

    // Col epilogue: thread t folds 2 columns over 16 row-groups (4w x 4q),
    // stores ONE partial per (block, col).
#pragma unroll
    for (int v = 0; v < 2; ++v) {
        int cj = (v << 8) + t;              // 0..511 within the j-half
        int c  = cj >> 7, u = (cj >> 4) & 7, mm = cj & 15;
        float s = 0.f;
        unsigned pk = 0u;
#pragma unroll
        for (int g = 0; g < 16; ++g) {      // g = w*4 + q
            float2 rd = tl[c * 2048 + ((g >> 2) * 8 + u) * 64 + (g & 3) * 16 + mm];
            s += rd.x;
            unsigned o = __float_as_uint(rd.y);
            pk = pk > o ? pk : o;
        }
        int gidx = (((bb << 4) + it) << 10) + (jh << 9) + cj;
        cps[gidx] = s;
        cpp[gidx] = pk;
    }
}

// Fold row partials (2 j-halves) and col partials (16 i-tiles) into the
// final stats arrays. Tie-break: umax on packed (bits|inv_index) keeps the
// smaller index on equal truncated value = first-occurrence, matching ref.
__global__ __launch_bounds__(256) void merge_kernel(
        const float* __restrict__ rps, const unsigned* __restrict__ rpp,
        const float* __restrict__ cps, const unsigned* __restrict__ cpp,
        float* __restrict__ row_sum, unsigned* __restrict__ row_pk,
        float* __restrict__ col_sum, unsigned* __restrict__ col_pk) {
    int p = blockIdx.x * 256 + threadIdx.x;   // 32768
    // rows: 2 partials
    float rs = rps[p] + rps[32768 + p];
    unsigned ra = rpp[p], rb = rpp[32768 + p];
    row_sum[p] = rs;
    row_pk[p]  = ra > rb ? ra : rb;
    // cols: 16 partials, stride 1024 dwords (j contiguous -> coalesced)
    int bb = p >> 10, j = p & 1023;
    const float*    cq = cps + (((size_t)bb << 14) + j);
    const unsigned* cr = cpp + (((size_t)bb << 14) + j);
    float s = 0.f;
    unsigned pk = 0u;
#pragma unroll
    for (int k = 0; k < 16; ++k) {
        s += cq[(size_t)k << 10];
        unsigned o = cr[(size_t)k << 10];
        pk = pk > o ? pk : o;
    }
    col_sum[p] = s;
    col_pk[p]  = pk;
}

// Reference broadcasting: trailing /(sum+EPS) factors are indexed by ELEMENT
// position, not by argmax. Writes per-block partials (no atomics, no init).
__global__ __launch_bounds__(256) void loss_kernel2(
        const float* __restrict__ row_sum, const unsigned* __restrict__ row_pk,
        const float* __restrict__ col_sum, const unsigned* __restrict__ col_pk,
        float* __restrict__ partial) {
    int t = blockIdx.x * 256 + threadIdx.x;
    float acc = 0.f;
#pragma unroll
    for (int it = 0; it < 4; ++it) {
        int p = t + it * 16384;
        if (p < NB * LL) {
            unsigned pk2 = row_pk[p];
            float m2 = __uint_as_float(pk2 & 0xFFFFFC00u);
            int j = 1023 - (int)(pk2 & 1023u);
            float s2 = row_sum[p];
            float s1 = col_sum[p];
            unsigned pk1 = col_pk[(p & ~1023) + j];
            float m1 = __uint_as_float(pk1 & 0xFFFFFC00u);
            acc += logf((m2 / (s2 + EPS)) * (m1 / (s1 + EPS)));
        } else {
            int p2 = p - NB * LL;
            unsigned pk1 = col_pk[p2];
            float m1 = __uint_as_float(pk1 & 0xFFFFFC00u);
            int i = 1023 - (int)(pk1 & 1023u);
            float s1 = col_sum[p2];
            float s2 = row_sum[p2];
            unsigned pk2 = row_pk[(p2 & ~1023) + i];
            float m2 = __uint_as_float(pk2 & 0xFFFFFC00u);
            acc += logf((m1 / (s1 + EPS)) * (m2 / (s2 + EPS)));
        }
    }
#pragma unroll
    for (int off = 32; off > 0; off >>= 1) acc += __shfl_down(acc, off, 64);
    __shared__ float wsum[4];
    int lane = threadIdx.x & 63, w = threadIdx.x >> 6;
    if (lane == 0) wsum[w] = acc;
    __syncthreads();
    if (threadIdx.x == 0)
        partial[blockIdx.x] = wsum[0] + wsum[1] + wsum[2] + wsum[3];
}

__global__ void finalize_kernel(const float* __restrict__ partial,
                                float* __restrict__ out) {
    float v = partial[threadIdx.x];
#pragma unroll
    for (int off = 32; off > 0; off >>= 1) v += __shfl_down(v, off, 64);
    if (threadIdx.x == 0) out[0] = -v / (float)(2 * NB * LL);
}

extern "C" void kernel_launch(void* const* d_in, const int* in_sizes, int n_in,
                              void* d_out, int out_size, void* d_ws, size_t ws_size,
                              hipStream_t stream) {
    const float* rgb = (const float*)d_in[0];
    const float* ir  = (const float*)d_in[1];
    char* wsb = (char*)d_ws;

    __bf16*   At      = (__bf16*)(wsb);
    __bf16*   Bt      = (__bf16*)(wsb + 4194304);
    float*    row_sum = (float*)(wsb + 8388608);
    float*    col_sum = (float*)(wsb + 8519680);
    unsigned* row_pk  = (unsigned*)(wsb + 8650752);
    unsigned* col_pk  = (unsigned*)(wsb + 8781824);
    float*    partial = (float*)(wsb + 8912896);
    float*    rps     = (float*)(wsb + 9437184);
    unsigned* rpp     = (unsigned*)(wsb + 9699328);
    float*    cps     = (float*)(wsb + 9961472);
    unsigned* cpp     = (unsigned*)(wsb + 12058624);

    transpose_norm_kernel<<<1024, 256, 0, stream>>>(rgb, ir, At, Bt);
    gemm_stats_kernel<<<1024, 256, 0, stream>>>(At, Bt, rps, rpp, cps, cpp);
    merge_kernel<<<128, 256, 0, stream>>>(rps, rpp, cps, cpp,
                                          row_sum, row_pk, col_sum, col_pk);
    loss_kernel2<<<64, 256, 0, stream>>>(row_sum, row_pk, col_sum, col_pk, partial);
    finalize_kernel<<<1, 64, 0, stream>>>(partial, (float*)d_out);
}